// Round 13
// baseline (374.051 us; speedup 1.0000x reference)
//
#include <hip/hip_runtime.h>
#include <hip/hip_bf16.h>
#include <hip/hip_fp8.h>

// DecoderBlock: B=4, S=2048, D=1024, DFF=4096. fp32 in/out.
// Round 13: R12 frozen + (a) PV1 2-way K-split (k_pv1, 512 balanced blocks,
// raw dispatch order, halves -> attnb/attnb2, LN1 sums), (b) y/Z transpose
// merged into one dispatch.

#define Bb 4
#define Ss 2048
#define Dd 1024
#define Ff 4096

typedef __attribute__((ext_vector_type(4))) float f32x4;
typedef __attribute__((ext_vector_type(8))) short bf16x8;
typedef __attribute__((ext_vector_type(2))) long i64x2;
typedef __attribute__((ext_vector_type(8))) unsigned short u16x8;
typedef __attribute__((ext_vector_type(4))) unsigned short u16x4;

__device__ __forceinline__ unsigned short f2bf(float f) {
  unsigned u = __float_as_uint(f);
  u += 0x7FFFu + ((u >> 16) & 1u);
  return (unsigned short)(u >> 16);
}
__device__ __forceinline__ float bf2f(unsigned short h) {
  return __uint_as_float(((unsigned)h) << 16);
}
__device__ __forceinline__ unsigned char f2f8(float f) {
  __hip_fp8_e4m3 q(f);
  return q.__x;
}
__device__ __forceinline__ int f8col(int c) {
  int g = c >> 6, b = c & 63, o = b >> 3, j = b & 7;
  return g * 64 + (2 * (o & 3) + (o >> 2)) * 8 + j;
}

__device__ __forceinline__ void gload_lds16(const void* g, void* l) {
  __builtin_amdgcn_global_load_lds((const __attribute__((address_space(1))) void*)g,
                                   (__attribute__((address_space(3))) void*)l, 16, 0, 0);
}

__device__ __forceinline__ int xcd8(int orig, int n) {
  int q = n >> 3, r = n & 7;
  int x = orig & 7;
  int base = x < r ? x * (q + 1) : r * (q + 1) + (x - r) * q;
  return base + (orig >> 3);
}

// ------------- merged y/Z transpose+cast: z<Bb -> y, else Z -------------
__global__ __launch_bounds__(256) void k_transpose2(const float* __restrict__ inA,
                                                    const float* __restrict__ inB,
                                                    unsigned short* __restrict__ outTA,
                                                    unsigned short* __restrict__ outTB,
                                                    unsigned char* __restrict__ out8A,
                                                    unsigned char* __restrict__ out8B,
                                                    int R, int C) {
  __shared__ float t[32][33];
  int z = blockIdx.z;
  bool second = z >= Bb;
  int b = second ? z - Bb : z;
  size_t bo = (size_t)b * R * C;
  const float* pin = (second ? inB : inA) + bo;
  unsigned short* poutT = (second ? outTB : outTA) + bo;
  unsigned char* pout8 = (second ? out8B : out8A) + bo;
  int c0 = blockIdx.x * 32, r0 = blockIdx.y * 32;
  int tx = threadIdx.x, ty = threadIdx.y;
#pragma unroll
  for (int i = 0; i < 4; i++) {
    float v = pin[(size_t)(r0 + ty + i * 8) * C + c0 + tx];
    t[ty + i * 8][tx] = v;
    pout8[(size_t)(r0 + ty + i * 8) * C + f8col(c0 + tx)] = f2f8(v);
  }
  __syncthreads();
#pragma unroll
  for (int i = 0; i < 4; i++)
    poutT[(size_t)(c0 + ty + i * 8) * R + r0 + tx] = f2bf(t[tx][ty + i * 8]);
}

// ------------- weight transpose+cast (fp32 -> bf16^T) -------------
__global__ __launch_bounds__(256) void k_transpose_cast(const float* __restrict__ in,
                                                        unsigned short* __restrict__ outT,
                                                        int R, int C) {
  __shared__ float t[32][33];
  const float* pin = in;
  unsigned short* poutT = outT;
  int c0 = blockIdx.x * 32, r0 = blockIdx.y * 32;
  int tx = threadIdx.x, ty = threadIdx.y;
#pragma unroll
  for (int i = 0; i < 4; i++)
    t[ty + i * 8][tx] = pin[(size_t)(r0 + ty + i * 8) * C + c0 + tx];
  __syncthreads();
#pragma unroll
  for (int i = 0; i < 4; i++)
    poutT[(size_t)(c0 + ty + i * 8) * R + r0 + tx] = f2bf(t[tx][ty + i * 8]);
}

// ---- shared machinery --------------------------------------------------
#define BAR() __builtin_amdgcn_s_barrier()
#define PRIO1() __builtin_amdgcn_s_setprio(1)
#define PRIO0() __builtin_amdgcn_s_setprio(0)

#define LDA8(arr, mh, bo)                                                       \
  {                                                                             \
    _Pragma("unroll") for (int j_ = 0; j_ < QM; ++j_) {                         \
      _Pragma("unroll") for (int kh_ = 0; kh_ < 2; ++kh_) {                     \
        arr[j_][kh_] =                                                          \
            *(const bf16x8*)(lds + (bo) + ((mh)*QM + j_) * 2048 + aof[kh_]);    \
      }                                                                         \
    }                                                                           \
  }

#define LDB8(arr, nh, bo)                                                       \
  {                                                                             \
    _Pragma("unroll") for (int n_ = 0; n_ < 2; ++n_) {                          \
      _Pragma("unroll") for (int kh_ = 0; kh_ < 2; ++kh_) {                     \
        arr[n_][kh_] =                                                          \
            *(const bf16x8*)(lds + (bo) + ((nh)*2 + n_) * 2048 + bof[kh_]);     \
      }                                                                         \
    }                                                                           \
  }

#define MMQ(aarr, barr, mh, nh)                                                 \
  {                                                                             \
    _Pragma("unroll") for (int j_ = 0; j_ < QM; ++j_) {                         \
      _Pragma("unroll") for (int n_ = 0; n_ < 2; ++n_) {                        \
        _Pragma("unroll") for (int kh_ = 0; kh_ < 2; ++kh_) {                   \
          acc[(mh)*QM + j_][(nh)*2 + n_] = __builtin_amdgcn_mfma_f32_16x16x32_bf16( \
              aarr[j_][kh_], barr[n_][kh_], acc[(mh)*QM + j_][(nh)*2 + n_], 0, 0, 0); \
        }                                                                       \
      }                                                                         \
    }                                                                           \
  }

#define LDAF8(arr, mh, bo)                                                      \
  {                                                                             \
    _Pragma("unroll") for (int j_ = 0; j_ < 4; ++j_)                            \
        arr[j_] = *(const i64x2*)(lds + (bo) + ((mh)*4 + j_) * 1024 + aofs);    \
  }
#define LDBF8(arr, nh, bo)                                                      \
  {                                                                             \
    _Pragma("unroll") for (int n_ = 0; n_ < 2; ++n_)                            \
        arr[n_] = *(const i64x2*)(lds + (bo) + ((nh)*2 + n_) * 1024 + bofs);    \
  }
#define MMQF8(aarr, barr, mh, nh)                                               \
  {                                                                             \
    _Pragma("unroll") for (int j_ = 0; j_ < 4; ++j_) {                          \
      _Pragma("unroll") for (int n_ = 0; n_ < 2; ++n_) {                        \
        _Pragma("unroll") for (int kh_ = 0; kh_ < 2; ++kh_) {                   \
          acc[(mh)*4 + j_][(nh)*2 + n_] = __builtin_amdgcn_mfma_f32_16x16x32_fp8_fp8( \
              aarr[j_][kh_], barr[n_][kh_], acc[(mh)*4 + j_][(nh)*2 + n_], 0, 0, 0);  \
        }                                                                       \
      }                                                                         \
    }                                                                           \
  }

// EPI: 0 *scale->bf16 | 2 bias+relu->bf16 | 6 (v+residB)->bf16 | 7 (v+bias+residB)->bf16
#define EPILOGUE(MR_, WMS_)                                                     \
  {                                                                             \
    const int colb = j0 + wc * 64 + fr;                                         \
    const int rowb = i0 + wr * (WMS_) + (kq << 2);                              \
    const size_t cb = (size_t)bz * bsC;                                         \
    _Pragma("unroll") for (int m = 0; m < (MR_); ++m) {                         \
      _Pragma("unroll") for (int r = 0; r < 4; ++r) {                           \
        size_t ro = cb + (size_t)(rowb + m * 16 + r) * ldc;                     \
        _Pragma("unroll") for (int n = 0; n < 4; ++n) {                         \
          float v = acc[m][n][r];                                               \
          int col = colb + n * 16;                                              \
          if (EPI == 0) Cb[ro + col] = f2bf(v * scale);                         \
          else if (EPI == 2) Cb[ro + col] = f2bf(fmaxf(v + bias[col], 0.f));    \
          else if (EPI == 6) Cb[ro + col] = f2bf(v + bf2f(residB[ro + col]));   \
          else Cb[ro + col] = f2bf(v + bias[col] + bf2f(residB[ro + col]));     \
        }                                                                       \
      }                                                                         \
    }                                                                           \
  }

// ========================= k_gemm8f8: fp8 scores, 256x256, 8-phase ===========
template <bool CAUSAL>
__global__ __launch_bounds__(512) void k_gemm8f8(
    const unsigned char* __restrict__ Ag, const unsigned char* __restrict__ Bg,
    unsigned short* __restrict__ Cb,
    int K, int lda, int ldb, int ldc, long bsA, long bsB, long bsC, float scale) {
  constexpr int ABYTES = 16384, BBYTES = 16384;
  __shared__ alignas(16) char lds[2 * ABYTES + 2 * BBYTES];

  int i0, j0;
  if (CAUSAL) {
    int t = xcd8(blockIdx.x, gridDim.x);
    int ti = (int)((sqrtf(8.f * t + 1.f) - 1.f) * 0.5f);
    while ((ti + 1) * (ti + 2) / 2 <= t) ++ti;
    while (ti * (ti + 1) / 2 > t) --ti;
    i0 = ti * 256;
    j0 = (t - ti * (ti + 1) / 2) * 256;
  } else {
    int lin = xcd8(blockIdx.y * gridDim.x + blockIdx.x, gridDim.x * gridDim.y);
    i0 = (lin / gridDim.x) * 256;
    j0 = (lin % gridDim.x) * 256;
  }
  int bz = blockIdx.z;
  Ag += (size_t)bz * bsA;
  Bg += (size_t)bz * bsB;

  const int nk = K / 64;
  const int niter = nk / 2;

  const int tid = threadIdx.x;
  const int w = tid >> 6, lane = tid & 63;
  const int wr = w >> 2, wc = w & 3;

  const int srow = tid >> 2;
  const int scs = (tid & 3) ^ ((tid >> 3) & 3);
  const unsigned char* As = Ag + (size_t)(i0 + srow) * lda + scs * 16;
  const unsigned char* Bs = Bg + (size_t)(j0 + srow) * ldb + scs * 16;

  auto stA = [&](int kt, int hf) {
    int ks = kt < nk ? kt : nk - 1;
    gload_lds16(As + (size_t)(hf * 128) * lda + ks * 64,
                lds + (kt & 1) * ABYTES + hf * 8192 + w * 1024);
  };
  auto stB = [&](int kt, int hf) {
    int ks = kt < nk ? kt : nk - 1;
    gload_lds16(Bs + (size_t)(hf * 128) * ldb + ks * 64,
                lds + 2 * ABYTES + (kt & 1) * BBYTES + hf * 8192 + w * 1024);
  };

  const int fr = lane & 15, kq = lane >> 4;
  const int rA = wr * 128 + fr;
  const int rB = wc * 64 + fr;
  const unsigned aofs = rA * 64 + ((kq ^ ((rA >> 1) & 3)) << 4);
  const unsigned bofs = rB * 64 + ((kq ^ ((rB >> 1) & 3)) << 4);
  constexpr int A0 = 0, A1 = ABYTES, B0 = 2 * ABYTES, B1 = 2 * ABYTES + BBYTES;

  f32x4 acc[8][4];
#pragma unroll
  for (int m = 0; m < 8; ++m)
#pragma unroll
    for (int n = 0; n < 4; ++n) acc[m][n] = (f32x4){0.f, 0.f, 0.f, 0.f};

  i64x2 a0[4], a1[4], b0[2], b1[2];

  stA(0, 0); stA(0, 1); stB(0, 0); stB(0, 1);
  stA(1, 0); stA(1, 1); stB(1, 0);
  asm volatile("s_waitcnt vmcnt(3)" ::: "memory");
  BAR();
  LDAF8(a0, 0, A0); LDBF8(b0, 0, B0);

  for (int t = 0; t < niter; ++t) {
    const int ka = 2 * t + 2, kb = 2 * t + 3;
    LDAF8(a1, 1, A0);
    stB(2 * t + 1, 1);
    BAR(); PRIO1(); MMQF8(a0, b0, 0, 0); PRIO0(); BAR();
    LDBF8(b1, 1, B0);
    stA(ka, 0);
    BAR(); PRIO1(); MMQF8(a1, b0, 1, 0); PRIO0(); BAR();
    stA(ka, 1);
    BAR(); PRIO1(); MMQF8(a0, b1, 0, 1); PRIO0(); BAR();
    stB(ka, 0);
    asm volatile("s_waitcnt vmcnt(3)" ::: "memory");
    BAR();
    LDAF8(a0, 0, A1); LDBF8(b0, 0, B1);
    PRIO1(); MMQF8(a1, b1, 1, 1); PRIO0(); BAR();
    LDAF8(a1, 1, A1);
    stB(ka, 1);
    BAR(); PRIO1(); MMQF8(a0, b0, 0, 0); PRIO0(); BAR();
    LDBF8(b1, 1, B1);
    stA(kb, 0);
    BAR(); PRIO1(); MMQF8(a1, b0, 1, 0); PRIO0(); BAR();
    stA(kb, 1);
    BAR(); PRIO1(); MMQF8(a0, b1, 0, 1); PRIO0(); BAR();
    stB(kb, 0);
    asm volatile("s_waitcnt vmcnt(3)" ::: "memory");
    BAR();
    LDAF8(a0, 0, A0); LDBF8(b0, 0, B0);
    PRIO1(); MMQF8(a1, b1, 1, 1); PRIO0(); BAR();
  }

  const int colb = j0 + wc * 64 + fr;
  const int rowb = i0 + wr * 128 + (kq << 2);
  const size_t cb = (size_t)bz * bsC;
#pragma unroll
  for (int m = 0; m < 8; ++m) {
#pragma unroll
    for (int r = 0; r < 4; ++r) {
      size_t ro = cb + (size_t)(rowb + m * 16 + r) * ldc;
#pragma unroll
      for (int n = 0; n < 4; ++n)
        Cb[ro + colb + n * 16] = f2bf(acc[m][n][r] * scale);
    }
  }
}

// ========================= k_gemm8: BMt=256, 8-phase bf16 (frozen) ===========
template <int EPI, bool CAUSAL>
__global__ __launch_bounds__(512) void k_gemm8(
    const unsigned short* __restrict__ Ag, const unsigned short* __restrict__ Bg,
    unsigned short* __restrict__ Cb,
    const float* __restrict__ bias, const unsigned short* __restrict__ residB,
    int K, int lda, int ldb, int ldc, long bsA, long bsB, long bsC, float scale) {
  constexpr int QM = 4;
  constexpr int ABYTES = 32768, BBYTES = 32768;
  __shared__ alignas(16) char lds[2 * ABYTES + 2 * BBYTES];

  int i0, j0;
  if (CAUSAL) {
    int t = xcd8(blockIdx.x, gridDim.x);
    int ti = (int)((sqrtf(8.f * t + 1.f) - 1.f) * 0.5f);
    while ((ti + 1) * (ti + 2) / 2 <= t) ++ti;
    while (ti * (ti + 1) / 2 > t) --ti;
    i0 = ti * 256;
    j0 = (t - ti * (ti + 1) / 2) * 256;
  } else {
    int lin = xcd8(blockIdx.y * gridDim.x + blockIdx.x, gridDim.x * gridDim.y);
    i0 = (lin / gridDim.x) * 256;
    j0 = (lin % gridDim.x) * 256;
  }
  int bz = blockIdx.z;
  Ag += (size_t)bz * bsA;
  Bg += (size_t)bz * bsB;

  const int nk = K / 64;
  const int niter = nk / 2;

  const int tid = threadIdx.x;
  const int w = tid >> 6, lane = tid & 63;
  const int wr = w >> 2, wc = w & 3;

  const int srow = (w << 3) + (lane >> 3);
  const int bcs = (lane & 7) ^ (lane >> 3);
  const unsigned short* As = Ag + (size_t)(i0 + srow) * lda + bcs * 8;
  const unsigned short* Bs = Bg + (size_t)(j0 + srow) * ldb + bcs * 8;
  char* ldsAw = lds + w * 1024;
  char* ldsBw = lds + 2 * ABYTES + w * 1024;

  auto stA = [&](int kt, int hf) {
    int ks = kt < nk ? kt : nk - 1;
#pragma unroll
    for (int l = 0; l < 2; ++l)
      gload_lds16(As + (size_t)(hf * 128 + l * 64) * lda + ks * 64,
                  ldsAw + (kt & 1) * ABYTES + hf * 128 * 128 + l * 8192);
  };
  auto stB = [&](int kt, int hf) {
    int ks = kt < nk ? kt : nk - 1;
#pragma unroll
    for (int l = 0; l < 2; ++l)
      gload_lds16(Bs + (size_t)(hf * 128 + l * 64) * ldb + ks * 64,
                  ldsBw + (kt & 1) * BBYTES + hf * 128 * 128 + l * 8192);
  };

  const int fr = lane & 15, kq = lane >> 4;
  const int rA = wr * 128 + fr;
  const int rB = wc * 64 + fr;
  unsigned aof[2], bof[2];
  aof[0] = rA * 128 + ((kq ^ (rA & 7)) << 4);
  aof[1] = rA * 128 + (((kq + 4) ^ (rA & 7)) << 4);
  bof[0] = 2 * ABYTES + rB * 128 + ((kq ^ (rB & 7)) << 4);
  bof[1] = 2 * ABYTES + rB * 128 + (((kq + 4) ^ (rB & 7)) << 4);
  constexpr int A0 = 0, A1 = ABYTES, B0 = 0, B1 = BBYTES;

  f32x4 acc[8][4];
#pragma unroll
  for (int m = 0; m < 8; ++m)
#pragma unroll
    for (int n = 0; n < 4; ++n) acc[m][n] = (f32x4){0.f, 0.f, 0.f, 0.f};

  bf16x8 a0[QM][2], a1[QM][2], b0[2][2], b1[2][2];

  stA(0, 0); stA(0, 1); stB(0, 0); stB(0, 1);
  stA(1, 0); stA(1, 1); stB(1, 0);
  asm volatile("s_waitcnt vmcnt(6)" ::: "memory");
  BAR();
  LDA8(a0, 0, A0); LDB8(b0, 0, B0);

  for (int t = 0; t < niter; ++t) {
    const int ka = 2 * t + 2, kb = 2 * t + 3;
    LDA8(a1, 1, A0);
    stB(2 * t + 1, 1);
    BAR(); PRIO1(); MMQ(a0, b0, 0, 0); PRIO0(); BAR();
    LDB8(b1, 1, B0);
    stA(ka, 0);
    BAR(); PRIO1(); MMQ(a1, b0, 1, 0); PRIO0(); BAR();
    stA(ka, 1);
    BAR(); PRIO1(); MMQ(a0, b1, 0, 1); PRIO0(); BAR();
    stB(ka, 0);
    asm volatile("s_waitcnt vmcnt(6)" ::: "memory");
    BAR();
    LDA8(a0, 0, A1); LDB8(b0, 0, B1);
    PRIO1(); MMQ(a1, b1, 1, 1); PRIO0(); BAR();
    LDA8(a1, 1, A1);
    stB(ka, 1);
    BAR(); PRIO1(); MMQ(a0, b0, 0, 0); PRIO0(); BAR();
    LDB8(b1, 1, B1);
    stA(kb, 0);
    BAR(); PRIO1(); MMQ(a1, b0, 1, 0); PRIO0(); BAR();
    stA(kb, 1);
    BAR(); PRIO1(); MMQ(a0, b1, 0, 1); PRIO0(); BAR();
    stB(kb, 0);
    asm volatile("s_waitcnt vmcnt(6)" ::: "memory");
    BAR();
    LDA8(a0, 0, A0); LDB8(b0, 0, B0);
    PRIO1(); MMQ(a1, b1, 1, 1); PRIO0(); BAR();
  }
  EPILOGUE(8, 128)
}

// ========================= k_gemm4: BMt=128, 4-phase bf16 (frozen) ===========
template <int EPI, bool KCAP>
__global__ __launch_bounds__(512) void k_gemm4(
    const unsigned short* __restrict__ Ag, const unsigned short* __restrict__ Bg,
    unsigned short* __restrict__ Cb,
    const float* __restrict__ bias, const unsigned short* __restrict__ residB,
    int K, int lda, int ldb, int ldc, long bsA, long bsB, long bsC, float scale) {
  constexpr int QM = 4;
  constexpr int ABYTES = 16384, BBYTES = 32768;
  __shared__ alignas(16) char lds[2 * ABYTES + 2 * BBYTES];

  int lin = xcd8(blockIdx.y * gridDim.x + blockIdx.x, gridDim.x * gridDim.y);
  int i0 = (lin / gridDim.x) * 128;
  int j0 = (lin % gridDim.x) * 256;
  int bz = blockIdx.z;
  Ag += (size_t)bz * bsA;
  Bg += (size_t)bz * bsB;

  int nk = K / 64;
  if (KCAP) {
    int cap = i0 / 64 + 2;
    nk = nk < cap ? nk : cap;
  }
  const int niter = nk / 2;

  const int tid = threadIdx.x;
  const int w = tid >> 6, lane = tid & 63;
  const int wr = w >> 2, wc = w & 3;

  const int srow = (w << 3) + (lane >> 3);
  const int bcs = (lane & 7) ^ (lane >> 3);
  const unsigned short* As = Ag + (size_t)(i0 + srow) * lda + bcs * 8;
  const unsigned short* Bs = Bg + (size_t)(j0 + srow) * ldb + bcs * 8;
  char* ldsAw = lds + w * 1024;
  char* ldsBw = lds + 2 * ABYTES + w * 1024;

  auto stA2 = [&](int kt) {
    int ks = kt < nk ? kt : nk - 1;
#pragma unroll
    for (int hf = 0; hf < 2; ++hf)
      gload_lds16(As + (size_t)(hf * 64) * lda + ks * 64,
                  ldsAw + (kt & 1) * ABYTES + hf * 64 * 128);
  };
  auto stBh = [&](int kt, int hf) {
    int ks = kt < nk ? kt : nk - 1;
#pragma unroll
    for (int l = 0; l < 2; ++l)
      gload_lds16(Bs + (size_t)(hf * 128 + l * 64) * ldb + ks * 64,
                  ldsBw + (kt & 1) * BBYTES + hf * 128 * 128 + l * 8192);
  };

  const int fr = lane & 15, kq = lane >> 4;
  const int rA = wr * 64 + fr;
  const int rB = wc * 64 + fr;
  unsigned aof[2], bof[2];
  aof[0] = rA * 128 + ((kq ^ (rA & 7)) << 4);
  aof[1] = rA * 128 + (((kq + 4) ^ (rA & 7)) << 4);
  bof[0] = 2 * ABYTES + rB * 128 + ((kq ^ (rB & 7)) << 4);
  bof[1] = 2 * ABYTES + rB * 128 + (((kq + 4) ^ (rB & 7)) << 4);
  constexpr int A0 = 0, A1 = ABYTES, B0 = 0, B1 = BBYTES;

  f32x4 acc[4][4];
#pragma unroll
  for (int m = 0; m < 4; ++m)
#pragma unroll
    for (int n = 0; n < 4; ++n) acc[m][n] = (f32x4){0.f, 0.f, 0.f, 0.f};

  bf16x8 a[QM][2], b0[2][2], b1[2][2];

  stA2(0); stBh(0, 0); stBh(0, 1);
  stA2(1); stBh(1, 0);
  asm volatile("s_waitcnt vmcnt(4)" ::: "memory");
  BAR();
  LDA8(a, 0, A0); LDB8(b0, 0, B0);

  for (int t = 0; t < niter; ++t) {
    const int ka = 2 * t + 2, kb = 2 * t + 3;
    LDB8(b1, 1, B0);
    stBh(2 * t + 1, 1);
    BAR(); PRIO1(); MMQ(a, b0, 0, 0); PRIO0(); BAR();
    stA2(ka); stBh(ka, 0);
    asm volatile("s_waitcnt vmcnt(4)" ::: "memory");
    BAR();
    PRIO1(); MMQ(a, b1, 0, 1); PRIO0();
    LDA8(a, 0, A1); LDB8(b0, 0, B1);
    BAR();
    LDB8(b1, 1, B1);
    stBh(ka, 1);
    BAR(); PRIO1(); MMQ(a, b0, 0, 0); PRIO0(); BAR();
    stA2(kb); stBh(kb, 0);
    asm volatile("s_waitcnt vmcnt(4)" ::: "memory");
    BAR();
    PRIO1(); MMQ(a, b1, 0, 1); PRIO0();
    LDA8(a, 0, A0); LDB8(b0, 0, B0);
    BAR();
  }
  EPILOGUE(4, 64)
}

// ========================= k_pv1: PV1 with 2-way K-split =====================
// grid (8, 16, Bb): x = col(4) + 4*kh(2); y = row stripe iy. cap = 2*iy+2
// K-tiles; half A = (iy+2)&~1 (even, <=16), half B = cap-A (even, may be 0).
// Raw dispatch order (NO xcd8): round-robin spreads every stripe across XCDs
// -> per-CU load ~ avg 17 K-tiles instead of max 32. kh0 -> attnb (+ y resid),
// kh1 -> attnb2 (plain). LN1 sums the halves.
__global__ __launch_bounds__(512) void k_pv1(
    const unsigned short* __restrict__ Ag, const unsigned short* __restrict__ Bg,
    unsigned short* __restrict__ C0, unsigned short* __restrict__ C1,
    const float* __restrict__ residF) {
  constexpr int QM = 4;
  constexpr int ABYTES = 16384, BBYTES = 32768;
  __shared__ alignas(16) char lds[2 * ABYTES + 2 * BBYTES];
  const int lda = Ss, ldb = Ss, ldc = Dd;

  const int xc = blockIdx.x & 3, kh = blockIdx.x >> 2;
  const int iy = blockIdx.y;
  const int i0 = iy * 128, j0 = xc * 256;
  const int bz = blockIdx.z;
  Ag += (size_t)bz * ((long)Ss * Ss);
  Bg += (size_t)bz * ((long)Dd * Ss);

  const int cap = 2 * iy + 2;
  const int nA = (iy + 2) & ~1;
  const int kbase = kh ? nA : 0;
  const int nkr = kh ? cap - nA : nA;  // even, 0..16
  const int niter = nkr / 2;

  const int tid = threadIdx.x;
  const int w = tid >> 6, lane = tid & 63;
  const int wr = w >> 2, wc = w & 3;

  const int srow = (w << 3) + (lane >> 3);
  const int bcs = (lane & 7) ^ (lane >> 3);
  const unsigned short* As = Ag + (size_t)(i0 + srow) * lda + bcs * 8;
  const unsigned short* Bs = Bg + (size_t)(j0 + srow) * ldb + bcs * 8;
  char* ldsAw = lds + w * 1024;
  char* ldsBw = lds + 2 * ABYTES + w * 1024;

  auto stA2 = [&](int kt) {
    int ks = kbase + (kt < nkr ? kt : (nkr > 0 ? nkr - 1 : 0));
#pragma unroll
    for (int hf = 0; hf < 2; ++hf)
      gload_lds16(As + (size_t)(hf * 64) * lda + ks * 64,
                  ldsAw + (kt & 1) * ABYTES + hf * 64 * 128);
  };
  auto stBh = [&](int kt, int hf) {
    int ks = kbase + (kt < nkr ? kt : (nkr > 0 ? nkr - 1 : 0));
#pragma unroll
    for (int l = 0; l < 2; ++l)
      gload_lds16(Bs + (size_t)(hf * 128 + l * 64) * ldb + ks * 64,
                  ldsBw + (kt & 1) * BBYTES + hf * 128 * 128 + l * 8192);
  };

  const int fr = lane & 15, kq = lane >> 4;
  const int rA = wr * 64 + fr;
  const int rB = wc * 64 + fr;
  unsigned aof[2], bof[2];
  aof[0] = rA * 128 + ((kq ^ (rA & 7)) << 4);
  aof[1] = rA * 128 + (((kq + 4) ^ (rA & 7)) << 4);
  bof[0] = 2 * ABYTES + rB * 128 + ((kq ^ (rB & 7)) << 4);
  bof[1] = 2 * ABYTES + rB * 128 + (((kq + 4) ^ (rB & 7)) << 4);
  constexpr int A0 = 0, A1 = ABYTES, B0 = 0, B1 = BBYTES;

  f32x4 acc[4][4];
#pragma unroll
  for (int m = 0; m < 4; ++m)
#pragma unroll
    for (int n = 0; n < 4; ++n) acc[m][n] = (f32x4){0.f, 0.f, 0.f, 0.f};

  bf16x8 a[QM][2], b0[2][2], b1[2][2];

  stA2(0); stBh(0, 0); stBh(0, 1);
  stA2(1); stBh(1, 0);
  asm volatile("s_waitcnt vmcnt(4)" ::: "memory");
  BAR();
  LDA8(a, 0, A0); LDB8(b0, 0, B0);

  for (int t = 0; t < niter; ++t) {
    const int ka = 2 * t + 2, kb = 2 * t + 3;
    LDB8(b1, 1, B0);
    stBh(2 * t + 1, 1);
    BAR(); PRIO1(); MMQ(a, b0, 0, 0); PRIO0(); BAR();
    stA2(ka); stBh(ka, 0);
    asm volatile("s_waitcnt vmcnt(4)" ::: "memory");
    BAR();
    PRIO1(); MMQ(a, b1, 0, 1); PRIO0();
    LDA8(a, 0, A1); LDB8(b0, 0, B1);
    BAR();
    LDB8(b1, 1, B1);
    stBh(ka, 1);
    BAR(); PRIO1(); MMQ(a, b0, 0, 0); PRIO0(); BAR();
    stA2(kb); stBh(kb, 0);
    asm volatile("s_waitcnt vmcnt(4)" ::: "memory");
    BAR();
    PRIO1(); MMQ(a, b1, 0, 1); PRIO0();
    LDA8(a, 0, A0); LDB8(b0, 0, B0);
    BAR();
  }

  // epilogue: kh0 -> C0 with fp32 y residual; kh1 -> C1 plain
  const int colb = j0 + wc * 64 + fr;
  const int rowb = i0 + wr * 64 + (kq << 2);
  const size_t cb = (size_t)bz * ((long)Ss * Dd);
  unsigned short* Cb = kh ? C1 : C0;
#pragma unroll
  for (int m = 0; m < 4; ++m) {
#pragma unroll
    for (int r = 0; r < 4; ++r) {
      size_t ro = cb + (size_t)(rowb + m * 16 + r) * ldc;
#pragma unroll
      for (int n = 0; n < 4; ++n) {
        float v = acc[m][n][r];
        int col = colb + n * 16;
        if (kh == 0) Cb[ro + col] = f2bf(v + residF[ro + col]);
        else Cb[ro + col] = f2bf(v);
      }
    }
  }
}

// ---------------- row softmax, bf16 scores -> bf16 P in place ----------------
template <bool CAUSAL>
__global__ __launch_bounds__(256) void k_softmax(unsigned short* __restrict__ scores) {
  int row = blockIdx.x;  // b*S + i
  int i = row & (Ss - 1);
  unsigned short* src = scores + (size_t)row * Ss;
  int nv = CAUSAL ? i + 1 : Ss;
  int nb = CAUSAL ? ((i & ~127) + 128) : Ss;
  int t = threadIdx.x;
  int w = t >> 6, lane = t & 63;
  bool act = t * 8 < nb;
  float v[8];
  float mx = -1e30f;
  if (act) {
    u16x8 raw = *(const u16x8*)(src + t * 8);
#pragma unroll
    for (int k = 0; k < 8; k++) {
      int j = t * 8 + k;
      v[k] = (j < nv) ? bf2f(raw[k]) : -1e30f;
      mx = fmaxf(mx, v[k]);
    }
  } else {
#pragma unroll
    for (int k = 0; k < 8; k++) v[k] = -1e30f;
  }
#pragma unroll
  for (int o = 32; o; o >>= 1) mx = fmaxf(mx, __shfl_xor(mx, o));
  __shared__ float red[8];
  if (lane == 0) red[w] = mx;
  __syncthreads();
  mx = fmaxf(fmaxf(red[0], red[1]), fmaxf(red[2], red[3]));
  float sum = 0.f;
#pragma unroll
  for (int k = 0; k < 8; k++) {
    float e = (v[k] > -1e29f) ? __expf(v[k] - mx) : 0.f;
    v[k] = e;
    sum += e;
  }
#pragma unroll
  for (int o = 32; o; o >>= 1) sum += __shfl_xor(sum, o);
  if (lane == 0) red[4 + w] = sum;
  __syncthreads();
  sum = red[4] + red[5] + red[6] + red[7];
  float inv = 1.f / sum;
  if (act) {
    u16x8 r;
#pragma unroll
    for (int k = 0; k < 8; k++) r[k] = f2bf(v[k] * inv);
    *(u16x8*)(src + t * 8) = r;
  }
}

// ---------------- LayerNorm (bf16 input, optional second bf16 addend) --------
// OM: 0 = fp32 out (final) | 1 = bf16 out | 2 = bf16 + fp8(f8col) outs
template <int OM>
__global__ __launch_bounds__(256) void k_ln(const unsigned short* __restrict__ a,
                                            const unsigned short* __restrict__ a2,
                                            const float* __restrict__ g,
                                            const float* __restrict__ be,
                                            float* __restrict__ outf,
                                            unsigned short* __restrict__ outb,
                                            unsigned char* __restrict__ out8) {
  int row = blockIdx.x;
  size_t o = (size_t)row * Dd;
  int t = threadIdx.x;
  u16x4 raw = *(const u16x4*)(a + o + t * 4);
  f32x4 x;
#pragma unroll
  for (int k = 0; k < 4; k++) x[k] = bf2f(raw[k]);
  if (a2) {
    u16x4 raw2 = *(const u16x4*)(a2 + o + t * 4);
#pragma unroll
    for (int k = 0; k < 4; k++) x[k] += bf2f(raw2[k]);
  }
  float s = x[0] + x[1] + x[2] + x[3];
  float q = x[0] * x[0] + x[1] * x[1] + x[2] * x[2] + x[3] * x[3];
  int w = t >> 6, lane = t & 63;
#pragma unroll
  for (int of = 32; of; of >>= 1) {
    s += __shfl_xor(s, of);
    q += __shfl_xor(q, of);
  }
  __shared__ float red[8];
  if (lane == 0) {
    red[w] = s;
    red[4 + w] = q;
  }
  __syncthreads();
  s = red[0] + red[1] + red[2] + red[3];
  q = red[4] + red[5] + red[6] + red[7];
  float mean = s * (1.f / Dd);
  float var = q * (1.f / Dd) - mean * mean;
  float rstd = rsqrtf(var + 1e-5f);
  f32x4 gv = *(const f32x4*)(g + t * 4);
  f32x4 bv = *(const f32x4*)(be + t * 4);
  f32x4 y;
#pragma unroll
  for (int k = 0; k < 4; k++) y[k] = (x[k] - mean) * rstd * gv[k] + bv[k];
  if (OM == 0) {
    *(f32x4*)(outf + o + t * 4) = y;
  } else {
    u16x4 r;
    r[0] = f2bf(y[0]); r[1] = f2bf(y[1]); r[2] = f2bf(y[2]); r[3] = f2bf(y[3]);
    *(u16x4*)(outb + o + t * 4) = r;
    if (OM == 2) {
      int cbyte = t * 4;
      int gq = cbyte >> 6, oo = (cbyte >> 3) & 7, j = cbyte & 7;
      int phys = gq * 64 + (2 * (oo & 3) + (oo >> 2)) * 8 + j;
      unsigned rr = (unsigned)f2f8(y[0]) | ((unsigned)f2f8(y[1]) << 8) |
                    ((unsigned)f2f8(y[2]) << 16) | ((unsigned)f2f8(y[3]) << 24);
      *(unsigned*)(out8 + (size_t)row * Dd + phys) = rr;
    }
  }
}

extern "C" void kernel_launch(void* const* d_in, const int* in_sizes, int n_in, void* d_out,
                              int out_size, void* d_ws, size_t ws_size, hipStream_t stream) {
  (void)in_sizes; (void)n_in; (void)out_size; (void)ws_size;
  const float* y   = (const float*)d_in[0];
  const float* Z   = (const float*)d_in[1];
  const float* w1  = (const float*)d_in[2];
  const float* b1  = (const float*)d_in[3];
  const float* w2  = (const float*)d_in[4];
  const float* b2  = (const float*)d_in[5];
  const float* g1  = (const float*)d_in[6];
  const float* be1 = (const float*)d_in[7];
  const float* g2  = (const float*)d_in[8];
  const float* be2 = (const float*)d_in[9];
  const float* g3  = (const float*)d_in[10];
  const float* be3 = (const float*)d_in[11];
  float* out = (float*)d_out;

  // ws layout (160MB), lifetime-audited (R12 + unchanged):
  //  slot0 @  0: y^T bf16 (PV1 B) -> y1b (LN1 out) -> FFN2 out (LN3 in)
  //  Zt @16, ybf @32, w1t @48, w2t @56, sc/h @64, y8 @96, Z8 @104, y18 @112
  //  d_out: [0,16MB) attnb (PV half-A + resid), [16,32MB) attnb2 (PV1 half-B)
  char* ws = (char*)d_ws;
  const size_t MB = 1024ull * 1024ull;
  unsigned short* T   = (unsigned short*)(ws);
  unsigned short* y1b = (unsigned short*)(ws);
  unsigned short* ffo = (unsigned short*)(ws);
  unsigned short* Zt  = (unsigned short*)(ws + 16 * MB);
  unsigned short* ybf = (unsigned short*)(ws + 32 * MB);
  unsigned short* w1t = (unsigned short*)(ws + 48 * MB);
  unsigned short* w2t = (unsigned short*)(ws + 56 * MB);
  unsigned short* sc  = (unsigned short*)(ws + 64 * MB);
  unsigned short* h   = (unsigned short*)(ws + 64 * MB);
  unsigned char* y8   = (unsigned char*)(ws + 96 * MB);
  unsigned char* Z8   = (unsigned char*)(ws + 104 * MB);
  unsigned char* y18  = (unsigned char*)(ws + 112 * MB);
  unsigned short* attnb  = (unsigned short*)d_out;
  unsigned short* attnb2 = (unsigned short*)((char*)d_out + 16 * MB);

  dim3 b256(256), b512(512);
  const float scl = 1.f / 32.f;
  const long SD = (long)Ss * Dd, SS = (long)Ss * Ss;

  // --- input prep up front (y+Z merged; weights) ---
  k_transpose2<<<dim3(Dd / 32, Ss / 32, 2 * Bb), dim3(32, 8), 0, stream>>>(
      y, Z, T, Zt, y8, Z8, Ss, Dd);
  k_transpose_cast<<<dim3(Ff / 32, Dd / 32, 1), dim3(32, 8), 0, stream>>>(w1, w1t, Dd, Ff);
  k_transpose_cast<<<dim3(Dd / 32, Ff / 32, 1), dim3(32, 8), 0, stream>>>(w2, w2t, Ff, Dd);

  // --- self-attention (scores fp8; PV1 K-split balanced) ---
  k_gemm8f8<true><<<dim3(36, 1, Bb), b512, 0, stream>>>(
      y8, y8, sc, Dd, Dd, Dd, Ss, SD, SD, SS, scl);
  k_softmax<true><<<dim3(Bb * Ss), b256, 0, stream>>>(sc);
  k_pv1<<<dim3(8, Ss / 128, Bb), b512, 0, stream>>>(sc, T, attnb, attnb2, y);
  k_ln<2><<<dim3(Bb * Ss), b256, 0, stream>>>(attnb, attnb2, g1, be1, nullptr, y1b, y18);

  // --- cross-attention (scores fp8) ---
  k_gemm8f8<false><<<dim3(Ss / 256, Ss / 256, Bb), b512, 0, stream>>>(
      y18, Z8, sc, Dd, Dd, Dd, Ss, SD, SD, SS, scl);
  k_softmax<false><<<dim3(Bb * Ss), b256, 0, stream>>>(sc);
  k_gemm4<6, false><<<dim3(Dd / 256, Ss / 128, Bb), b512, 0, stream>>>(
      sc, Zt, attnb, nullptr, y1b, Ss, Ss, Ss, Dd, SS, SD, SD, 1.f);
  k_ln<1><<<dim3(Bb * Ss), b256, 0, stream>>>(attnb, nullptr, g2, be2, nullptr, ybf, nullptr);

  // --- FFN (bf16, frozen) ---
  k_gemm8<2, false><<<dim3(Ff / 256, (Bb * Ss) / 256, 1), b512, 0, stream>>>(
      ybf, w1t, h, b1, nullptr, Dd, Dd, Dd, Ff, 0L, 0L, 0L, 1.f);
  k_gemm4<7, false><<<dim3(Dd / 256, (Bb * Ss) / 128, 1), b512, 0, stream>>>(
      h, w2t, ffo, b2, ybf, Ff, Ff, Ff, Dd, 0L, 0L, 0L, 1.f);
  k_ln<0><<<dim3(Bb * Ss), b256, 0, stream>>>(ffo, nullptr, g3, be3, out, nullptr, nullptr);
}

// Round 14
// 350.009 us; speedup vs baseline: 1.0687x; 1.0687x over previous
//
#include <hip/hip_runtime.h>
#include <hip/hip_bf16.h>
#include <hip/hip_fp8.h>

// DecoderBlock: B=4, S=2048, D=1024, DFF=4096. fp32 in/out.
// Round 14: R12 base (353.5us) + PV1 antipodal-stripe balance (k_pv1b):
// 256 blocks / ONE dispatch round; light block (iy<8) does own tile K[0,2iy+2)
// + helper partial of heavy stripe 15-iy K[16,2jy+2) -> 18 K-tiles; heavy
// block does K[0,16). LN1 adds helper buffer for heavy stripes only.

#define Bb 4
#define Ss 2048
#define Dd 1024
#define Ff 4096

typedef __attribute__((ext_vector_type(4))) float f32x4;
typedef __attribute__((ext_vector_type(8))) short bf16x8;
typedef __attribute__((ext_vector_type(2))) long i64x2;
typedef __attribute__((ext_vector_type(8))) unsigned short u16x8;
typedef __attribute__((ext_vector_type(4))) unsigned short u16x4;

__device__ __forceinline__ unsigned short f2bf(float f) {
  unsigned u = __float_as_uint(f);
  u += 0x7FFFu + ((u >> 16) & 1u);
  return (unsigned short)(u >> 16);
}
__device__ __forceinline__ float bf2f(unsigned short h) {
  return __uint_as_float(((unsigned)h) << 16);
}
__device__ __forceinline__ unsigned char f2f8(float f) {
  __hip_fp8_e4m3 q(f);
  return q.__x;
}
__device__ __forceinline__ int f8col(int c) {
  int g = c >> 6, b = c & 63, o = b >> 3, j = b & 7;
  return g * 64 + (2 * (o & 3) + (o >> 2)) * 8 + j;
}

__device__ __forceinline__ void gload_lds16(const void* g, void* l) {
  __builtin_amdgcn_global_load_lds((const __attribute__((address_space(1))) void*)g,
                                   (__attribute__((address_space(3))) void*)l, 16, 0, 0);
}

__device__ __forceinline__ int xcd8(int orig, int n) {
  int q = n >> 3, r = n & 7;
  int x = orig & 7;
  int base = x < r ? x * (q + 1) : r * (q + 1) + (x - r) * q;
  return base + (orig >> 3);
}

// ---------------- transpose+cast: in[R][C] fp32 -> outT[C][R] bf16 (+opt fp8 row-major) --
__global__ __launch_bounds__(256) void k_transpose_cast(const float* __restrict__ in,
                                                        unsigned short* __restrict__ outT,
                                                        unsigned char* __restrict__ out8,
                                                        int R, int C) {
  __shared__ float t[32][33];
  size_t bo = (size_t)blockIdx.z * R * C;
  const float* pin = in + bo;
  unsigned short* poutT = outT + bo;
  unsigned char* pout8 = out8 ? out8 + bo : nullptr;
  int c0 = blockIdx.x * 32, r0 = blockIdx.y * 32;
  int tx = threadIdx.x, ty = threadIdx.y;
#pragma unroll
  for (int i = 0; i < 4; i++) {
    float v = pin[(size_t)(r0 + ty + i * 8) * C + c0 + tx];
    t[ty + i * 8][tx] = v;
    if (pout8) pout8[(size_t)(r0 + ty + i * 8) * C + f8col(c0 + tx)] = f2f8(v);
  }
  __syncthreads();
#pragma unroll
  for (int i = 0; i < 4; i++)
    poutT[(size_t)(c0 + ty + i * 8) * R + r0 + tx] = f2bf(t[tx][ty + i * 8]);
}

// ---- shared machinery --------------------------------------------------
#define BAR() __builtin_amdgcn_s_barrier()
#define PRIO1() __builtin_amdgcn_s_setprio(1)
#define PRIO0() __builtin_amdgcn_s_setprio(0)

#define LDA8(arr, mh, bo)                                                       \
  {                                                                             \
    _Pragma("unroll") for (int j_ = 0; j_ < QM; ++j_) {                         \
      _Pragma("unroll") for (int kh_ = 0; kh_ < 2; ++kh_) {                     \
        arr[j_][kh_] =                                                          \
            *(const bf16x8*)(lds + (bo) + ((mh)*QM + j_) * 2048 + aof[kh_]);    \
      }                                                                         \
    }                                                                           \
  }

#define LDB8(arr, nh, bo)                                                       \
  {                                                                             \
    _Pragma("unroll") for (int n_ = 0; n_ < 2; ++n_) {                          \
      _Pragma("unroll") for (int kh_ = 0; kh_ < 2; ++kh_) {                     \
        arr[n_][kh_] =                                                          \
            *(const bf16x8*)(lds + (bo) + ((nh)*2 + n_) * 2048 + bof[kh_]);     \
      }                                                                         \
    }                                                                           \
  }

#define MMQ(aarr, barr, mh, nh)                                                 \
  {                                                                             \
    _Pragma("unroll") for (int j_ = 0; j_ < QM; ++j_) {                         \
      _Pragma("unroll") for (int n_ = 0; n_ < 2; ++n_) {                        \
        _Pragma("unroll") for (int kh_ = 0; kh_ < 2; ++kh_) {                   \
          acc[(mh)*QM + j_][(nh)*2 + n_] = __builtin_amdgcn_mfma_f32_16x16x32_bf16( \
              aarr[j_][kh_], barr[n_][kh_], acc[(mh)*QM + j_][(nh)*2 + n_], 0, 0, 0); \
        }                                                                       \
      }                                                                         \
    }                                                                           \
  }

#define LDAF8(arr, mh, bo)                                                      \
  {                                                                             \
    _Pragma("unroll") for (int j_ = 0; j_ < 4; ++j_)                            \
        arr[j_] = *(const i64x2*)(lds + (bo) + ((mh)*4 + j_) * 1024 + aofs);    \
  }
#define LDBF8(arr, nh, bo)                                                      \
  {                                                                             \
    _Pragma("unroll") for (int n_ = 0; n_ < 2; ++n_)                            \
        arr[n_] = *(const i64x2*)(lds + (bo) + ((nh)*2 + n_) * 1024 + bofs);    \
  }
#define MMQF8(aarr, barr, mh, nh)                                               \
  {                                                                             \
    _Pragma("unroll") for (int j_ = 0; j_ < 4; ++j_) {                          \
      _Pragma("unroll") for (int n_ = 0; n_ < 2; ++n_) {                        \
        _Pragma("unroll") for (int kh_ = 0; kh_ < 2; ++kh_) {                   \
          acc[(mh)*4 + j_][(nh)*2 + n_] = __builtin_amdgcn_mfma_f32_16x16x32_fp8_fp8( \
              aarr[j_][kh_], barr[n_][kh_], acc[(mh)*4 + j_][(nh)*2 + n_], 0, 0, 0);  \
        }                                                                       \
      }                                                                         \
    }                                                                           \
  }

// EPI: 0 *scale->bf16 | 2 bias+relu->bf16 | 6 (v+residB)->bf16 | 7 (v+bias+residB)->bf16
#define EPILOGUE(MR_, WMS_)                                                     \
  {                                                                             \
    const int colb = j0 + wc * 64 + fr;                                         \
    const int rowb = i0 + wr * (WMS_) + (kq << 2);                              \
    const size_t cb = (size_t)bz * bsC;                                         \
    _Pragma("unroll") for (int m = 0; m < (MR_); ++m) {                         \
      _Pragma("unroll") for (int r = 0; r < 4; ++r) {                           \
        size_t ro = cb + (size_t)(rowb + m * 16 + r) * ldc;                     \
        _Pragma("unroll") for (int n = 0; n < 4; ++n) {                         \
          float v = acc[m][n][r];                                               \
          int col = colb + n * 16;                                              \
          if (EPI == 0) Cb[ro + col] = f2bf(v * scale);                         \
          else if (EPI == 2) Cb[ro + col] = f2bf(fmaxf(v + bias[col], 0.f));    \
          else if (EPI == 6) Cb[ro + col] = f2bf(v + bf2f(residB[ro + col]));   \
          else Cb[ro + col] = f2bf(v + bias[col] + bf2f(residB[ro + col]));     \
        }                                                                       \
      }                                                                         \
    }                                                                           \
  }

// ========================= k_gemm8f8: fp8 scores, 256x256, 8-phase ===========
template <bool CAUSAL>
__global__ __launch_bounds__(512) void k_gemm8f8(
    const unsigned char* __restrict__ Ag, const unsigned char* __restrict__ Bg,
    unsigned short* __restrict__ Cb,
    int K, int lda, int ldb, int ldc, long bsA, long bsB, long bsC, float scale) {
  constexpr int ABYTES = 16384, BBYTES = 16384;
  __shared__ alignas(16) char lds[2 * ABYTES + 2 * BBYTES];

  int i0, j0;
  if (CAUSAL) {
    int t = xcd8(blockIdx.x, gridDim.x);
    int ti = (int)((sqrtf(8.f * t + 1.f) - 1.f) * 0.5f);
    while ((ti + 1) * (ti + 2) / 2 <= t) ++ti;
    while (ti * (ti + 1) / 2 > t) --ti;
    i0 = ti * 256;
    j0 = (t - ti * (ti + 1) / 2) * 256;
  } else {
    int lin = xcd8(blockIdx.y * gridDim.x + blockIdx.x, gridDim.x * gridDim.y);
    i0 = (lin / gridDim.x) * 256;
    j0 = (lin % gridDim.x) * 256;
  }
  int bz = blockIdx.z;
  Ag += (size_t)bz * bsA;
  Bg += (size_t)bz * bsB;

  const int nk = K / 64;
  const int niter = nk / 2;

  const int tid = threadIdx.x;
  const int w = tid >> 6, lane = tid & 63;
  const int wr = w >> 2, wc = w & 3;

  const int srow = tid >> 2;
  const int scs = (tid & 3) ^ ((tid >> 3) & 3);
  const unsigned char* As = Ag + (size_t)(i0 + srow) * lda + scs * 16;
  const unsigned char* Bs = Bg + (size_t)(j0 + srow) * ldb + scs * 16;

  auto stA = [&](int kt, int hf) {
    int ks = kt < nk ? kt : nk - 1;
    gload_lds16(As + (size_t)(hf * 128) * lda + ks * 64,
                lds + (kt & 1) * ABYTES + hf * 8192 + w * 1024);
  };
  auto stB = [&](int kt, int hf) {
    int ks = kt < nk ? kt : nk - 1;
    gload_lds16(Bs + (size_t)(hf * 128) * ldb + ks * 64,
                lds + 2 * ABYTES + (kt & 1) * BBYTES + hf * 8192 + w * 1024);
  };

  const int fr = lane & 15, kq = lane >> 4;
  const int rA = wr * 128 + fr;
  const int rB = wc * 64 + fr;
  const unsigned aofs = rA * 64 + ((kq ^ ((rA >> 1) & 3)) << 4);
  const unsigned bofs = rB * 64 + ((kq ^ ((rB >> 1) & 3)) << 4);
  constexpr int A0 = 0, A1 = ABYTES, B0 = 2 * ABYTES, B1 = 2 * ABYTES + BBYTES;

  f32x4 acc[8][4];
#pragma unroll
  for (int m = 0; m < 8; ++m)
#pragma unroll
    for (int n = 0; n < 4; ++n) acc[m][n] = (f32x4){0.f, 0.f, 0.f, 0.f};

  i64x2 a0[4], a1[4], b0[2], b1[2];

  stA(0, 0); stA(0, 1); stB(0, 0); stB(0, 1);
  stA(1, 0); stA(1, 1); stB(1, 0);
  asm volatile("s_waitcnt vmcnt(3)" ::: "memory");
  BAR();
  LDAF8(a0, 0, A0); LDBF8(b0, 0, B0);

  for (int t = 0; t < niter; ++t) {
    const int ka = 2 * t + 2, kb = 2 * t + 3;
    LDAF8(a1, 1, A0);
    stB(2 * t + 1, 1);
    BAR(); PRIO1(); MMQF8(a0, b0, 0, 0); PRIO0(); BAR();
    LDBF8(b1, 1, B0);
    stA(ka, 0);
    BAR(); PRIO1(); MMQF8(a1, b0, 1, 0); PRIO0(); BAR();
    stA(ka, 1);
    BAR(); PRIO1(); MMQF8(a0, b1, 0, 1); PRIO0(); BAR();
    stB(ka, 0);
    asm volatile("s_waitcnt vmcnt(3)" ::: "memory");
    BAR();
    LDAF8(a0, 0, A1); LDBF8(b0, 0, B1);
    PRIO1(); MMQF8(a1, b1, 1, 1); PRIO0(); BAR();
    LDAF8(a1, 1, A1);
    stB(ka, 1);
    BAR(); PRIO1(); MMQF8(a0, b0, 0, 0); PRIO0(); BAR();
    LDBF8(b1, 1, B1);
    stA(kb, 0);
    BAR(); PRIO1(); MMQF8(a1, b0, 1, 0); PRIO0(); BAR();
    stA(kb, 1);
    BAR(); PRIO1(); MMQF8(a0, b1, 0, 1); PRIO0(); BAR();
    stB(kb, 0);
    asm volatile("s_waitcnt vmcnt(3)" ::: "memory");
    BAR();
    LDAF8(a0, 0, A0); LDBF8(b0, 0, B0);
    PRIO1(); MMQF8(a1, b1, 1, 1); PRIO0(); BAR();
  }

  const int colb = j0 + wc * 64 + fr;
  const int rowb = i0 + wr * 128 + (kq << 2);
  const size_t cb = (size_t)bz * bsC;
#pragma unroll
  for (int m = 0; m < 8; ++m) {
#pragma unroll
    for (int r = 0; r < 4; ++r) {
      size_t ro = cb + (size_t)(rowb + m * 16 + r) * ldc;
#pragma unroll
      for (int n = 0; n < 4; ++n)
        Cb[ro + colb + n * 16] = f2bf(acc[m][n][r] * scale);
    }
  }
}

// ========================= k_gemm8: BMt=256, 8-phase bf16 (frozen) ===========
template <int EPI, bool CAUSAL>
__global__ __launch_bounds__(512) void k_gemm8(
    const unsigned short* __restrict__ Ag, const unsigned short* __restrict__ Bg,
    unsigned short* __restrict__ Cb,
    const float* __restrict__ bias, const unsigned short* __restrict__ residB,
    int K, int lda, int ldb, int ldc, long bsA, long bsB, long bsC, float scale) {
  constexpr int QM = 4;
  constexpr int ABYTES = 32768, BBYTES = 32768;
  __shared__ alignas(16) char lds[2 * ABYTES + 2 * BBYTES];

  int i0, j0;
  if (CAUSAL) {
    int t = xcd8(blockIdx.x, gridDim.x);
    int ti = (int)((sqrtf(8.f * t + 1.f) - 1.f) * 0.5f);
    while ((ti + 1) * (ti + 2) / 2 <= t) ++ti;
    while (ti * (ti + 1) / 2 > t) --ti;
    i0 = ti * 256;
    j0 = (t - ti * (ti + 1) / 2) * 256;
  } else {
    int lin = xcd8(blockIdx.y * gridDim.x + blockIdx.x, gridDim.x * gridDim.y);
    i0 = (lin / gridDim.x) * 256;
    j0 = (lin % gridDim.x) * 256;
  }
  int bz = blockIdx.z;
  Ag += (size_t)bz * bsA;
  Bg += (size_t)bz * bsB;

  const int nk = K / 64;
  const int niter = nk / 2;

  const int tid = threadIdx.x;
  const int w = tid >> 6, lane = tid & 63;
  const int wr = w >> 2, wc = w & 3;

  const int srow = (w << 3) + (lane >> 3);
  const int bcs = (lane & 7) ^ (lane >> 3);
  const unsigned short* As = Ag + (size_t)(i0 + srow) * lda + bcs * 8;
  const unsigned short* Bs = Bg + (size_t)(j0 + srow) * ldb + bcs * 8;
  char* ldsAw = lds + w * 1024;
  char* ldsBw = lds + 2 * ABYTES + w * 1024;

  auto stA = [&](int kt, int hf) {
    int ks = kt < nk ? kt : nk - 1;
#pragma unroll
    for (int l = 0; l < 2; ++l)
      gload_lds16(As + (size_t)(hf * 128 + l * 64) * lda + ks * 64,
                  ldsAw + (kt & 1) * ABYTES + hf * 128 * 128 + l * 8192);
  };
  auto stB = [&](int kt, int hf) {
    int ks = kt < nk ? kt : nk - 1;
#pragma unroll
    for (int l = 0; l < 2; ++l)
      gload_lds16(Bs + (size_t)(hf * 128 + l * 64) * ldb + ks * 64,
                  ldsBw + (kt & 1) * BBYTES + hf * 128 * 128 + l * 8192);
  };

  const int fr = lane & 15, kq = lane >> 4;
  const int rA = wr * 128 + fr;
  const int rB = wc * 64 + fr;
  unsigned aof[2], bof[2];
  aof[0] = rA * 128 + ((kq ^ (rA & 7)) << 4);
  aof[1] = rA * 128 + (((kq + 4) ^ (rA & 7)) << 4);
  bof[0] = 2 * ABYTES + rB * 128 + ((kq ^ (rB & 7)) << 4);
  bof[1] = 2 * ABYTES + rB * 128 + (((kq + 4) ^ (rB & 7)) << 4);
  constexpr int A0 = 0, A1 = ABYTES, B0 = 0, B1 = BBYTES;

  f32x4 acc[8][4];
#pragma unroll
  for (int m = 0; m < 8; ++m)
#pragma unroll
    for (int n = 0; n < 4; ++n) acc[m][n] = (f32x4){0.f, 0.f, 0.f, 0.f};

  bf16x8 a0[QM][2], a1[QM][2], b0[2][2], b1[2][2];

  stA(0, 0); stA(0, 1); stB(0, 0); stB(0, 1);
  stA(1, 0); stA(1, 1); stB(1, 0);
  asm volatile("s_waitcnt vmcnt(6)" ::: "memory");
  BAR();
  LDA8(a0, 0, A0); LDB8(b0, 0, B0);

  for (int t = 0; t < niter; ++t) {
    const int ka = 2 * t + 2, kb = 2 * t + 3;
    LDA8(a1, 1, A0);
    stB(2 * t + 1, 1);
    BAR(); PRIO1(); MMQ(a0, b0, 0, 0); PRIO0(); BAR();
    LDB8(b1, 1, B0);
    stA(ka, 0);
    BAR(); PRIO1(); MMQ(a1, b0, 1, 0); PRIO0(); BAR();
    stA(ka, 1);
    BAR(); PRIO1(); MMQ(a0, b1, 0, 1); PRIO0(); BAR();
    stB(ka, 0);
    asm volatile("s_waitcnt vmcnt(6)" ::: "memory");
    BAR();
    LDA8(a0, 0, A1); LDB8(b0, 0, B1);
    PRIO1(); MMQ(a1, b1, 1, 1); PRIO0(); BAR();
    LDA8(a1, 1, A1);
    stB(ka, 1);
    BAR(); PRIO1(); MMQ(a0, b0, 0, 0); PRIO0(); BAR();
    LDB8(b1, 1, B1);
    stA(kb, 0);
    BAR(); PRIO1(); MMQ(a1, b0, 1, 0); PRIO0(); BAR();
    stA(kb, 1);
    BAR(); PRIO1(); MMQ(a0, b1, 0, 1); PRIO0(); BAR();
    stB(kb, 0);
    asm volatile("s_waitcnt vmcnt(6)" ::: "memory");
    BAR();
    LDA8(a0, 0, A0); LDB8(b0, 0, B0);
    PRIO1(); MMQ(a1, b1, 1, 1); PRIO0(); BAR();
  }
  EPILOGUE(8, 128)
}

// ========================= k_gemm4: BMt=128, 4-phase bf16 (frozen) ===========
template <int EPI>
__global__ __launch_bounds__(512) void k_gemm4(
    const unsigned short* __restrict__ Ag, const unsigned short* __restrict__ Bg,
    unsigned short* __restrict__ Cb,
    const float* __restrict__ bias, const unsigned short* __restrict__ residB,
    int K, int lda, int ldb, int ldc, long bsA, long bsB, long bsC, float scale) {
  constexpr int QM = 4;
  constexpr int ABYTES = 16384, BBYTES = 32768;
  __shared__ alignas(16) char lds[2 * ABYTES + 2 * BBYTES];

  int lin = xcd8(blockIdx.y * gridDim.x + blockIdx.x, gridDim.x * gridDim.y);
  int i0 = (lin / gridDim.x) * 128;
  int j0 = (lin % gridDim.x) * 256;
  int bz = blockIdx.z;
  Ag += (size_t)bz * bsA;
  Bg += (size_t)bz * bsB;

  const int nk = K / 64;
  const int niter = nk / 2;

  const int tid = threadIdx.x;
  const int w = tid >> 6, lane = tid & 63;
  const int wr = w >> 2, wc = w & 3;

  const int srow = (w << 3) + (lane >> 3);
  const int bcs = (lane & 7) ^ (lane >> 3);
  const unsigned short* As = Ag + (size_t)(i0 + srow) * lda + bcs * 8;
  const unsigned short* Bs = Bg + (size_t)(j0 + srow) * ldb + bcs * 8;
  char* ldsAw = lds + w * 1024;
  char* ldsBw = lds + 2 * ABYTES + w * 1024;

  auto stA2 = [&](int kt) {
    int ks = kt < nk ? kt : nk - 1;
#pragma unroll
    for (int hf = 0; hf < 2; ++hf)
      gload_lds16(As + (size_t)(hf * 64) * lda + ks * 64,
                  ldsAw + (kt & 1) * ABYTES + hf * 64 * 128);
  };
  auto stBh = [&](int kt, int hf) {
    int ks = kt < nk ? kt : nk - 1;
#pragma unroll
    for (int l = 0; l < 2; ++l)
      gload_lds16(Bs + (size_t)(hf * 128 + l * 64) * ldb + ks * 64,
                  ldsBw + (kt & 1) * BBYTES + hf * 128 * 128 + l * 8192);
  };

  const int fr = lane & 15, kq = lane >> 4;
  const int rA = wr * 64 + fr;
  const int rB = wc * 64 + fr;
  unsigned aof[2], bof[2];
  aof[0] = rA * 128 + ((kq ^ (rA & 7)) << 4);
  aof[1] = rA * 128 + (((kq + 4) ^ (rA & 7)) << 4);
  bof[0] = 2 * ABYTES + rB * 128 + ((kq ^ (rB & 7)) << 4);
  bof[1] = 2 * ABYTES + rB * 128 + (((kq + 4) ^ (rB & 7)) << 4);
  constexpr int A0 = 0, A1 = ABYTES, B0 = 0, B1 = BBYTES;

  f32x4 acc[4][4];
#pragma unroll
  for (int m = 0; m < 4; ++m)
#pragma unroll
    for (int n = 0; n < 4; ++n) acc[m][n] = (f32x4){0.f, 0.f, 0.f, 0.f};

  bf16x8 a[QM][2], b0[2][2], b1[2][2];

  stA2(0); stBh(0, 0); stBh(0, 1);
  stA2(1); stBh(1, 0);
  asm volatile("s_waitcnt vmcnt(4)" ::: "memory");
  BAR();
  LDA8(a, 0, A0); LDB8(b0, 0, B0);

  for (int t = 0; t < niter; ++t) {
    const int ka = 2 * t + 2, kb = 2 * t + 3;
    LDB8(b1, 1, B0);
    stBh(2 * t + 1, 1);
    BAR(); PRIO1(); MMQ(a, b0, 0, 0); PRIO0(); BAR();
    stA2(ka); stBh(ka, 0);
    asm volatile("s_waitcnt vmcnt(4)" ::: "memory");
    BAR();
    PRIO1(); MMQ(a, b1, 0, 1); PRIO0();
    LDA8(a, 0, A1); LDB8(b0, 0, B1);
    BAR();
    LDB8(b1, 1, B1);
    stBh(ka, 1);
    BAR(); PRIO1(); MMQ(a, b0, 0, 0); PRIO0(); BAR();
    stA2(kb); stBh(kb, 0);
    asm volatile("s_waitcnt vmcnt(4)" ::: "memory");
    BAR();
    PRIO1(); MMQ(a, b1, 0, 1); PRIO0();
    LDA8(a, 0, A0); LDB8(b0, 0, B0);
    BAR();
  }
  EPILOGUE(4, 64)
}

// ========================= k_pv1b: PV1, antipodal-stripe balanced ===========
// grid (4, 16, Bb) = 256 blocks, ONE dispatch round (1 block/CU @ 96KB LDS).
// heavy (iy>=8): own tile K[0,16) -> C0 (+fp32 resid).
// light (iy<8):  own tile K[0,2iy+2) -> C0 (+resid), THEN helper partial of
//   stripe jy=15-iy over K[16,2jy+2) -> C1 (plain). Max 18 K-tiles/block.
// LN1 adds C1 only for heavy stripes ((i>>7)>=8). Full drain between sub-GEMMs
// (stale tail-clamp stages / trailing ds_reads would race the 2nd prologue).
__global__ __launch_bounds__(512) void k_pv1b(
    const unsigned short* __restrict__ Pg, const unsigned short* __restrict__ Vt,
    unsigned short* __restrict__ C0, unsigned short* __restrict__ C1,
    const float* __restrict__ residF) {
  constexpr int QM = 4;
  constexpr int ABYTES = 16384, BBYTES = 32768;
  __shared__ alignas(16) char lds[2 * ABYTES + 2 * BBYTES];
  const int lda = Ss, ldb = Ss, ldc = Dd;

  const int xc = blockIdx.x, iy = blockIdx.y, bz = blockIdx.z;
  const int j0 = xc * 256;
  const unsigned short* Ag0 = Pg + (size_t)bz * ((long)Ss * Ss);
  const unsigned short* Bg = Vt + (size_t)bz * ((long)Dd * Ss);

  const int tid = threadIdx.x;
  const int w = tid >> 6, lane = tid & 63;
  const int wr = w >> 2, wc = w & 3;
  const int srow = (w << 3) + (lane >> 3);
  const int bcs = (lane & 7) ^ (lane >> 3);
  const unsigned short* Bs = Bg + (size_t)(j0 + srow) * ldb + bcs * 8;
  char* ldsAw = lds + w * 1024;
  char* ldsBw = lds + 2 * ABYTES + w * 1024;

  const int fr = lane & 15, kq = lane >> 4;
  const int rA = wr * 64 + fr;
  const int rB = wc * 64 + fr;
  unsigned aof[2], bof[2];
  aof[0] = rA * 128 + ((kq ^ (rA & 7)) << 4);
  aof[1] = rA * 128 + (((kq + 4) ^ (rA & 7)) << 4);
  bof[0] = 2 * ABYTES + rB * 128 + ((kq ^ (rB & 7)) << 4);
  bof[1] = 2 * ABYTES + rB * 128 + (((kq + 4) ^ (rB & 7)) << 4);
  constexpr int A0 = 0, A1 = ABYTES, B0 = 0, B1 = BBYTES;

  auto runGemm = [&](int i0, int kbase, int nkr, unsigned short* Cb, bool addres) {
    // full drain: prior sub-GEMM's in-flight stages/reads must not race our LDS
    asm volatile("s_waitcnt vmcnt(0) lgkmcnt(0)" ::: "memory");
    BAR();
    const unsigned short* As = Ag0 + (size_t)(i0 + srow) * lda + bcs * 8;
    auto stA2 = [&](int kt) {
      int ks = kbase + (kt < nkr ? kt : nkr - 1);
#pragma unroll
      for (int hf = 0; hf < 2; ++hf)
        gload_lds16(As + (size_t)(hf * 64) * lda + ks * 64,
                    ldsAw + (kt & 1) * ABYTES + hf * 64 * 128);
    };
    auto stBh = [&](int kt, int hf) {
      int ks = kbase + (kt < nkr ? kt : nkr - 1);
#pragma unroll
      for (int l = 0; l < 2; ++l)
        gload_lds16(Bs + (size_t)(hf * 128 + l * 64) * ldb + ks * 64,
                    ldsBw + (kt & 1) * BBYTES + hf * 128 * 128 + l * 8192);
    };

    f32x4 acc[4][4];
#pragma unroll
    for (int m = 0; m < 4; ++m)
#pragma unroll
      for (int n = 0; n < 4; ++n) acc[m][n] = (f32x4){0.f, 0.f, 0.f, 0.f};
    bf16x8 a[QM][2], b0[2][2], b1[2][2];

    stA2(0); stBh(0, 0); stBh(0, 1);
    stA2(1); stBh(1, 0);
    asm volatile("s_waitcnt vmcnt(4)" ::: "memory");
    BAR();
    LDA8(a, 0, A0); LDB8(b0, 0, B0);

    const int niter = nkr / 2;
    for (int t = 0; t < niter; ++t) {
      const int ka = 2 * t + 2, kb = 2 * t + 3;
      LDB8(b1, 1, B0);
      stBh(2 * t + 1, 1);
      BAR(); PRIO1(); MMQ(a, b0, 0, 0); PRIO0(); BAR();
      stA2(ka); stBh(ka, 0);
      asm volatile("s_waitcnt vmcnt(4)" ::: "memory");
      BAR();
      PRIO1(); MMQ(a, b1, 0, 1); PRIO0();
      LDA8(a, 0, A1); LDB8(b0, 0, B1);
      BAR();
      LDB8(b1, 1, B1);
      stBh(ka, 1);
      BAR(); PRIO1(); MMQ(a, b0, 0, 0); PRIO0(); BAR();
      stA2(kb); stBh(kb, 0);
      asm volatile("s_waitcnt vmcnt(4)" ::: "memory");
      BAR();
      PRIO1(); MMQ(a, b1, 0, 1); PRIO0();
      LDA8(a, 0, A0); LDB8(b0, 0, B0);
      BAR();
    }

    const int colb = j0 + wc * 64 + fr;
    const int rowb = i0 + wr * 64 + (kq << 2);
    const size_t cb = (size_t)bz * ((long)Ss * Dd);
#pragma unroll
    for (int m = 0; m < 4; ++m) {
#pragma unroll
      for (int r = 0; r < 4; ++r) {
        size_t ro = cb + (size_t)(rowb + m * 16 + r) * ldc;
#pragma unroll
        for (int n = 0; n < 4; ++n) {
          float v = acc[m][n][r];
          int col = colb + n * 16;
          if (addres) Cb[ro + col] = f2bf(v + residF[ro + col]);
          else Cb[ro + col] = f2bf(v);
        }
      }
    }
  };

  if (iy >= 8) {
    runGemm(iy * 128, 0, 16, C0, true);          // heavy: 16 K-tiles
  } else {
    runGemm(iy * 128, 0, 2 * iy + 2, C0, true);  // light own: 2..16
    const int jy = 15 - iy;
    runGemm(jy * 128, 16, 2 * jy - 14, C1, false);  // helper: 2..16 (sum 18)
  }
}

// ---------------- row softmax, bf16 scores -> bf16 P in place ----------------
template <bool CAUSAL>
__global__ __launch_bounds__(256) void k_softmax(unsigned short* __restrict__ scores) {
  int row = blockIdx.x;  // b*S + i
  int i = row & (Ss - 1);
  unsigned short* src = scores + (size_t)row * Ss;
  int nv = CAUSAL ? i + 1 : Ss;
  int nb = CAUSAL ? ((i & ~127) + 128) : Ss;
  int t = threadIdx.x;
  int w = t >> 6, lane = t & 63;
  bool act = t * 8 < nb;
  float v[8];
  float mx = -1e30f;
  if (act) {
    u16x8 raw = *(const u16x8*)(src + t * 8);
#pragma unroll
    for (int k = 0; k < 8; k++) {
      int j = t * 8 + k;
      v[k] = (j < nv) ? bf2f(raw[k]) : -1e30f;
      mx = fmaxf(mx, v[k]);
    }
  } else {
#pragma unroll
    for (int k = 0; k < 8; k++) v[k] = -1e30f;
  }
#pragma unroll
  for (int o = 32; o; o >>= 1) mx = fmaxf(mx, __shfl_xor(mx, o));
  __shared__ float red[8];
  if (lane == 0) red[w] = mx;
  __syncthreads();
  mx = fmaxf(fmaxf(red[0], red[1]), fmaxf(red[2], red[3]));
  float sum = 0.f;
#pragma unroll
  for (int k = 0; k < 8; k++) {
    float e = (v[k] > -1e29f) ? __expf(v[k] - mx) : 0.f;
    v[k] = e;
    sum += e;
  }
#pragma unroll
  for (int o = 32; o; o >>= 1) sum += __shfl_xor(sum, o);
  if (lane == 0) red[4 + w] = sum;
  __syncthreads();
  sum = red[4] + red[5] + red[6] + red[7];
  float inv = 1.f / sum;
  if (act) {
    u16x8 r;
#pragma unroll
    for (int k = 0; k < 8; k++) r[k] = f2bf(v[k] * inv);
    *(u16x8*)(src + t * 8) = r;
  }
}

// ---------------- LayerNorm (bf16 input; optional heavy-stripe addend a2) ----
// OM: 0 = fp32 out (final) | 1 = bf16 out | 2 = bf16 + fp8(f8col) outs
template <int OM>
__global__ __launch_bounds__(256) void k_ln(const unsigned short* __restrict__ a,
                                            const unsigned short* __restrict__ a2,
                                            const float* __restrict__ g,
                                            const float* __restrict__ be,
                                            float* __restrict__ outf,
                                            unsigned short* __restrict__ outb,
                                            unsigned char* __restrict__ out8) {
  int row = blockIdx.x;
  size_t o = (size_t)row * Dd;
  int t = threadIdx.x;
  u16x4 raw = *(const u16x4*)(a + o + t * 4);
  f32x4 x;
#pragma unroll
  for (int k = 0; k < 4; k++) x[k] = bf2f(raw[k]);
  if (a2 && ((row & (Ss - 1)) >> 7) >= 8) {  // heavy stripes only (PV1 split)
    u16x4 raw2 = *(const u16x4*)(a2 + o + t * 4);
#pragma unroll
    for (int k = 0; k < 4; k++) x[k] += bf2f(raw2[k]);
  }
  float s = x[0] + x[1] + x[2] + x[3];
  float q = x[0] * x[0] + x[1] * x[1] + x[2] * x[2] + x[3] * x[3];
  int w = t >> 6, lane = t & 63;
#pragma unroll
  for (int of = 32; of; of >>= 1) {
    s += __shfl_xor(s, of);
    q += __shfl_xor(q, of);
  }
  __shared__ float red[8];
  if (lane == 0) {
    red[w] = s;
    red[4 + w] = q;
  }
  __syncthreads();
  s = red[0] + red[1] + red[2] + red[3];
  q = red[4] + red[5] + red[6] + red[7];
  float mean = s * (1.f / Dd);
  float var = q * (1.f / Dd) - mean * mean;
  float rstd = rsqrtf(var + 1e-5f);
  f32x4 gv = *(const f32x4*)(g + t * 4);
  f32x4 bv = *(const f32x4*)(be + t * 4);
  f32x4 y;
#pragma unroll
  for (int k = 0; k < 4; k++) y[k] = (x[k] - mean) * rstd * gv[k] + bv[k];
  if (OM == 0) {
    *(f32x4*)(outf + o + t * 4) = y;
  } else {
    u16x4 r;
    r[0] = f2bf(y[0]); r[1] = f2bf(y[1]); r[2] = f2bf(y[2]); r[3] = f2bf(y[3]);
    *(u16x4*)(outb + o + t * 4) = r;
    if (OM == 2) {
      int cbyte = t * 4;
      int gq = cbyte >> 6, oo = (cbyte >> 3) & 7, j = cbyte & 7;
      int phys = gq * 64 + (2 * (oo & 3) + (oo >> 2)) * 8 + j;
      unsigned rr = (unsigned)f2f8(y[0]) | ((unsigned)f2f8(y[1]) << 8) |
                    ((unsigned)f2f8(y[2]) << 16) | ((unsigned)f2f8(y[3]) << 24);
      *(unsigned*)(out8 + (size_t)row * Dd + phys) = rr;
    }
  }
}

extern "C" void kernel_launch(void* const* d_in, const int* in_sizes, int n_in, void* d_out,
                              int out_size, void* d_ws, size_t ws_size, hipStream_t stream) {
  (void)in_sizes; (void)n_in; (void)out_size; (void)ws_size;
  const float* y   = (const float*)d_in[0];
  const float* Z   = (const float*)d_in[1];
  const float* w1  = (const float*)d_in[2];
  const float* b1  = (const float*)d_in[3];
  const float* w2  = (const float*)d_in[4];
  const float* b2  = (const float*)d_in[5];
  const float* g1  = (const float*)d_in[6];
  const float* be1 = (const float*)d_in[7];
  const float* g2  = (const float*)d_in[8];
  const float* be2 = (const float*)d_in[9];
  const float* g3  = (const float*)d_in[10];
  const float* be3 = (const float*)d_in[11];
  float* out = (float*)d_out;

  // ws layout (160MB), lifetime-audited (R12):
  //  slot0 @  0: y^T bf16 (PV1 B) -> y1b (LN1 out) -> FFN2 out (LN3 in)
  //  Zt @16, ybf @32, w1t @48, w2t @56, sc/h @64, y8 @96, Z8 @104, y18 @112
  //  d_out: [0,16MB) attnb, [16,32MB) attnb2 (PV1 helper partials)
  char* ws = (char*)d_ws;
  const size_t MB = 1024ull * 1024ull;
  unsigned short* T   = (unsigned short*)(ws);
  unsigned short* y1b = (unsigned short*)(ws);
  unsigned short* ffo = (unsigned short*)(ws);
  unsigned short* Zt  = (unsigned short*)(ws + 16 * MB);
  unsigned short* ybf = (unsigned short*)(ws + 32 * MB);
  unsigned short* w1t = (unsigned short*)(ws + 48 * MB);
  unsigned short* w2t = (unsigned short*)(ws + 56 * MB);
  unsigned short* sc  = (unsigned short*)(ws + 64 * MB);
  unsigned short* h   = (unsigned short*)(ws + 64 * MB);
  unsigned char* y8   = (unsigned char*)(ws + 96 * MB);
  unsigned char* Z8   = (unsigned char*)(ws + 104 * MB);
  unsigned char* y18  = (unsigned char*)(ws + 112 * MB);
  unsigned short* attnb  = (unsigned short*)d_out;
  unsigned short* attnb2 = (unsigned short*)((char*)d_out + 16 * MB);

  dim3 b256(256), b512(512);
  const float scl = 1.f / 32.f;
  const long SD = (long)Ss * Dd, SS = (long)Ss * Ss;

  // --- input prep up front (R12 form) ---
  k_transpose_cast<<<dim3(Dd / 32, Ss / 32, Bb), dim3(32, 8), 0, stream>>>(y, T, y8, Ss, Dd);
  k_transpose_cast<<<dim3(Dd / 32, Ss / 32, Bb), dim3(32, 8), 0, stream>>>(Z, Zt, Z8, Ss, Dd);
  k_transpose_cast<<<dim3(Ff / 32, Dd / 32, 1), dim3(32, 8), 0, stream>>>(w1, w1t, nullptr, Dd, Ff);
  k_transpose_cast<<<dim3(Dd / 32, Ff / 32, 1), dim3(32, 8), 0, stream>>>(w2, w2t, nullptr, Ff, Dd);

  // --- self-attention (scores fp8; PV1 balanced one-round) ---
  k_gemm8f8<true><<<dim3(36, 1, Bb), b512, 0, stream>>>(
      y8, y8, sc, Dd, Dd, Dd, Ss, SD, SD, SS, scl);
  k_softmax<true><<<dim3(Bb * Ss), b256, 0, stream>>>(sc);
  k_pv1b<<<dim3(4, 16, Bb), b512, 0, stream>>>(sc, T, attnb, attnb2, y);
  k_ln<2><<<dim3(Bb * Ss), b256, 0, stream>>>(attnb, attnb2, g1, be1, nullptr, y1b, y18);

  // --- cross-attention (scores fp8) ---
  k_gemm8f8<false><<<dim3(Ss / 256, Ss / 256, Bb), b512, 0, stream>>>(
      y18, Z8, sc, Dd, Dd, Dd, Ss, SD, SD, SS, scl);
  k_softmax<false><<<dim3(Bb * Ss), b256, 0, stream>>>(sc);
  k_gemm4<6><<<dim3(Dd / 256, Ss / 128, Bb), b512, 0, stream>>>(
      sc, Zt, attnb, nullptr, y1b, Ss, Ss, Ss, Dd, SS, SD, SD, 1.f);
  k_ln<1><<<dim3(Bb * Ss), b256, 0, stream>>>(attnb, nullptr, g2, be2, nullptr, ybf, nullptr);

  // --- FFN (bf16, frozen) ---
  k_gemm8<2, false><<<dim3(Ff / 256, (Bb * Ss) / 256, 1), b512, 0, stream>>>(
      ybf, w1t, h, b1, nullptr, Dd, Dd, Dd, Ff, 0L, 0L, 0L, 1.f);
  k_gemm4<7><<<dim3(Dd / 256, (Bb * Ss) / 128, 1), b512, 0, stream>>>(
      h, w2t, ffo, b2, ybf, Ff, Ff, Ff, Dd, 0L, 0L, 0L, 1.f);
  k_ln<0><<<dim3(Bb * Ss), b256, 0, stream>>>(ffo, nullptr, g3, be3, out, nullptr, nullptr);
}